// Round 4
// baseline (497.790 us; speedup 1.0000x reference)
//
#include <hip/hip_runtime.h>
#include <math.h>

#define B    64
#define CHI  20
#define DD   65536             // C*H*W = 64*32*32
#define CHUNKS 64
#define CHUNK  (DD / CHUNKS)   // 1024 floats = 4 KiB per frame per block

static_assert(CHUNK / 4 == 256, "one float4 per thread per frame");
static_assert(256 * 21 * 4 + CHI * 4 < 65536, "k_apply LDS fits");

// ---------------------------------------------------------------------------
// Kernel 1: partial dot products  scores[b][c] = dot(frames[b][19], frames[b][c])
// grid = B*CHUNKS = 4096 blocks, 256 threads. Each block: one (batch, 4 KiB chunk).
// One float4 per frame per thread -> ~20 in-flight loads, low VGPR, full occupancy.
// Writes partials[b][chunk][c] (no atomics -> deterministic).
// ---------------------------------------------------------------------------
__global__ __launch_bounds__(256) void k_scores(const float* __restrict__ x,
                                                float* __restrict__ partials) {
    const int blk = blockIdx.x;
    const int b   = blk / CHUNKS;   // increasing batch order: tail stays L3-resident
    const int ch  = blk % CHUNKS;
    const int tid = threadIdx.x;

    const float4* xb = (const float4*)(x + (size_t)b * CHI * DD);
    const int f4    = DD / 4;                  // 16384 float4 per frame
    const int base4 = ch * (CHUNK / 4) + tid;  // this thread's float4 within a frame

    const float4 l = xb[(size_t)19 * f4 + base4];   // last frame, kept in registers

    float acc[CHI];
    acc[19] = l.x*l.x + l.y*l.y + l.z*l.z + l.w*l.w;

    #pragma unroll
    for (int c = 0; c < 19; ++c) {
        float4 v = xb[(size_t)c * f4 + base4];
        acc[c] = l.x*v.x + l.y*v.y + l.z*v.z + l.w*v.w;
    }

    // per-wave shuffle reduction (wave = 64 lanes)
    #pragma unroll
    for (int c = 0; c < CHI; ++c) {
        float v = acc[c];
        #pragma unroll
        for (int off = 32; off > 0; off >>= 1) v += __shfl_down(v, off, 64);
        acc[c] = v;
    }

    __shared__ float lds[4][CHI];
    const int wave = tid >> 6, lane = tid & 63;
    if (lane == 0) {
        #pragma unroll
        for (int c = 0; c < CHI; ++c) lds[wave][c] = acc[c];
    }
    __syncthreads();
    if (tid < CHI) {
        float s = lds[0][tid] + lds[1][tid] + lds[2][tid] + lds[3][tid];
        partials[((size_t)b * CHUNKS + ch) * CHI + tid] = s;
    }
}

// ---------------------------------------------------------------------------
// Kernel 2 (fused): softmax (recomputed per block from partials, L2-resident)
// + result[b][d] = sum_c x_flat[b][d*20+c] * alpha[b][c].
// Block stages a contiguous 20 KiB region (256 outputs x 20 floats) into LDS
// with dense float4 loads, then each thread reads its 20 floats via a
// stride-21 padded layout (21 odd -> 2-way bank aliasing = free).
// Batches processed in REVERSE order so the tail of phase 1's stream
// (still resident in the 256 MiB L3) is re-read first.
// grid = B*256 blocks x 256 threads.
// ---------------------------------------------------------------------------
__global__ __launch_bounds__(256) void k_apply(const float* __restrict__ x,
                                               const float* __restrict__ partials,
                                               float* __restrict__ out) {
    const int b   = (B - 1) - (int)(blockIdx.x >> 8);   // reversed batch order
    const int blk = blockIdx.x & 255;
    const int t   = threadIdx.x;

    __shared__ float lds[256 * 21];   // element j -> lds[j + j/20] == [d_local*21 + c]
    __shared__ float a_sm[CHI];

    // issue the staging loads first so they overlap the softmax compute
    const float4* src =
        (const float4*)(x + (size_t)b * CHI * DD + (size_t)blk * 256 * CHI);
    float4 vv[5];
    #pragma unroll
    for (int w = 0; w < 5; ++w) vv[w] = src[w * 256 + t];

    // wave 0: recompute alpha for this batch (identical math to the old k_softmax)
    if (t < 64) {
        const int lane = t;
        float sv = 0.0f;
        float s  = -INFINITY;
        if (lane < CHI) {
            #pragma unroll 8
            for (int k = 0; k < CHUNKS; ++k)
                sv += partials[((size_t)b * CHUNKS + k) * CHI + lane];
            sv /= (float)CHI;
            s = sv;
        }
        float m = s;
        #pragma unroll
        for (int off = 1; off < 64; off <<= 1) m = fmaxf(m, __shfl_xor(m, off, 64));
        float e = (lane < CHI) ? expf(sv - m) : 0.0f;
        float sum = e;
        #pragma unroll
        for (int off = 1; off < 64; off <<= 1) sum += __shfl_xor(sum, off, 64);
        if (lane < CHI) a_sm[lane] = e / sum;
    }

    // stage the 20 KiB region to LDS with the stride-21 padded layout
    #pragma unroll
    for (int w = 0; w < 5; ++w) {
        const int f = w * 256 + t;      // float4 index within the region
        const int j = 4 * f;            // j%20 in {0,4,8,12,16} -> no pad crossing
        const int p = j / 20;           // pad amount (= d_local)
        lds[j + p + 0] = vv[w].x;
        lds[j + p + 1] = vv[w].y;
        lds[j + p + 2] = vv[w].z;
        lds[j + p + 3] = vv[w].w;
    }

    __syncthreads();

    const int base = t * 21;
    float sum = 0.0f;
    #pragma unroll
    for (int c = 0; c < CHI; ++c) sum += lds[base + c] * a_sm[c];  // a_sm: broadcast, free

    out[(size_t)b * DD + (size_t)blk * 256 + t] = sum;
}

extern "C" void kernel_launch(void* const* d_in, const int* in_sizes, int n_in,
                              void* d_out, int out_size, void* d_ws, size_t ws_size,
                              hipStream_t stream) {
    const float* x = (const float*)d_in[0];
    float* out = (float*)d_out;

    float* partials = (float*)d_ws;    // B*CHUNKS*CHI floats = 327 KB

    k_scores<<<B * CHUNKS, 256, 0, stream>>>(x, partials);
    k_apply <<<B * 256,    256, 0, stream>>>(x, partials, out);
}

// Round 7
// 489.844 us; speedup vs baseline: 1.0162x; 1.0162x over previous
//
#include <hip/hip_runtime.h>
#include <math.h>

#define B    64
#define CHI  20
#define DD   65536             // C*H*W = 64*32*32
#define CHUNKS 64              // chunks per batch (k_scores)
#define CHUNK  (DD / CHUNKS)   // 1024 floats = 4 KiB per frame per block

static_assert(CHUNK / 4 == 256, "one float4 per thread per frame");
static_assert(256 * 21 * 4 < 65536, "k_apply LDS fits");

// ---------------------------------------------------------------------------
// Kernel 1: partial dot products  scores[b][c] = dot(frames[b][19], frames[b][c])
// grid = B*CHUNKS = 4096 blocks, 256 threads. Each block: one (batch, 4 KiB chunk).
// One float4 per frame per thread; writes partials[b][chunk][c] (no atomics).
// ---------------------------------------------------------------------------
__global__ __launch_bounds__(256) void k_scores(const float* __restrict__ x,
                                                float* __restrict__ partials) {
    const int blk = blockIdx.x;
    const int b   = blk / CHUNKS;
    const int ch  = blk % CHUNKS;
    const int tid = threadIdx.x;

    const float4* xb = (const float4*)(x + (size_t)b * CHI * DD);
    const int f4    = DD / 4;                  // 16384 float4 per frame
    const int base4 = ch * (CHUNK / 4) + tid;  // this thread's float4 within a frame

    const float4 l = xb[(size_t)19 * f4 + base4];   // last frame, kept in registers

    float acc[CHI];
    acc[19] = l.x*l.x + l.y*l.y + l.z*l.z + l.w*l.w;

    #pragma unroll
    for (int c = 0; c < 19; ++c) {
        float4 v = xb[(size_t)c * f4 + base4];
        acc[c] = l.x*v.x + l.y*v.y + l.z*v.z + l.w*v.w;
    }

    // per-wave shuffle reduction (wave = 64 lanes)
    #pragma unroll
    for (int c = 0; c < CHI; ++c) {
        float v = acc[c];
        #pragma unroll
        for (int off = 32; off > 0; off >>= 1) v += __shfl_down(v, off, 64);
        acc[c] = v;
    }

    __shared__ float lds[4][CHI];
    const int wave = tid >> 6, lane = tid & 63;
    if (lane == 0) {
        #pragma unroll
        for (int c = 0; c < CHI; ++c) lds[wave][c] = acc[c];
    }
    __syncthreads();
    if (tid < CHI) {
        float s = lds[0][tid] + lds[1][tid] + lds[2][tid] + lds[3][tid];
        partials[((size_t)b * CHUNKS + ch) * CHI + tid] = s;
    }
}

// ---------------------------------------------------------------------------
// Kernel 2: reduce partials over chunks, /chi, softmax over chi -> alpha[b][c]
// grid = B blocks x 64 threads (one wave). ~3 us, L2-resident.
// ---------------------------------------------------------------------------
__global__ __launch_bounds__(64) void k_softmax(const float* __restrict__ partials,
                                                float* __restrict__ alpha) {
    const int b = blockIdx.x;
    const int lane = threadIdx.x;

    float sv = 0.0f;
    float s = -INFINITY;
    if (lane < CHI) {
        #pragma unroll 8
        for (int k = 0; k < CHUNKS; ++k)
            sv += partials[((size_t)b * CHUNKS + k) * CHI + lane];
        sv /= (float)CHI;
        s = sv;
    }
    float m = s;
    #pragma unroll
    for (int off = 1; off < 64; off <<= 1) m = fmaxf(m, __shfl_xor(m, off, 64));
    float e = (lane < CHI) ? expf(sv - m) : 0.0f;
    float sum = e;
    #pragma unroll
    for (int off = 1; off < 64; off <<= 1) sum += __shfl_xor(sum, off, 64);
    if (lane < CHI) alpha[(size_t)b * CHI + lane] = e / sum;
}

// ---------------------------------------------------------------------------
// Kernel 3 (CORRECT reinterpreted-view contraction):
//   result[b][d] = sum_c x_flat[b][d*20 + c] * alpha[b][c]
// Each output consumes 20 CONSECUTIVE floats (the (B,D,chi) reshape view —
// NOT the frames[b][c][d] transpose; see round-6 failure).
// Block stages a contiguous 20 KiB region (256 outputs x 20 floats) into LDS
// with dense float4 loads, then each thread reads its 20 floats via a
// stride-21 padded layout (21 odd -> 2-way bank aliasing = free).
// Batches in REVERSE order so phase-1's tail (L3-resident) is re-read first.
// grid = B*256 blocks x 256 threads.
// ---------------------------------------------------------------------------
__global__ __launch_bounds__(256) void k_apply(const float* __restrict__ x,
                                               const float* __restrict__ alpha,
                                               float* __restrict__ out) {
    const int b   = (B - 1) - (int)(blockIdx.x >> 8);   // reversed batch order
    const int blk = blockIdx.x & 255;
    const int t   = threadIdx.x;

    __shared__ float lds[256 * 21];   // element j -> lds[j + j/20] == [d_local*21 + c]

    const float4* src =
        (const float4*)(x + (size_t)b * CHI * DD + (size_t)blk * 256 * CHI);

    #pragma unroll
    for (int w = 0; w < 5; ++w) {
        const int f = w * 256 + t;      // float4 index within the 20 KiB region
        float4 v = src[f];
        const int j = 4 * f;            // j%20 in {0,4,8,12,16} -> no pad crossing
        const int p = j / 20;           // pad amount (= d_local of element j)
        lds[j + p + 0] = v.x;
        lds[j + p + 1] = v.y;
        lds[j + p + 2] = v.z;
        lds[j + p + 3] = v.w;
    }

    // alpha for this batch: 80 B uniform, 16B-aligned (b*80 % 16 == 0)
    const float* ab = alpha + (size_t)b * CHI;
    float a[CHI];
    #pragma unroll
    for (int k = 0; k < 5; ++k) {
        float4 v = ((const float4*)ab)[k];
        a[4*k+0] = v.x; a[4*k+1] = v.y; a[4*k+2] = v.z; a[4*k+3] = v.w;
    }

    __syncthreads();

    const int base = t * 21;
    float sum = 0.0f;
    #pragma unroll
    for (int c = 0; c < CHI; ++c) sum += lds[base + c] * a[c];

    out[(size_t)b * DD + (size_t)blk * 256 + t] = sum;
}

extern "C" void kernel_launch(void* const* d_in, const int* in_sizes, int n_in,
                              void* d_out, int out_size, void* d_ws, size_t ws_size,
                              hipStream_t stream) {
    const float* x = (const float*)d_in[0];
    float* out = (float*)d_out;

    float* partials = (float*)d_ws;                        // B*CHUNKS*CHI floats
    float* alpha    = partials + (size_t)B * CHUNKS * CHI; // B*CHI floats

    k_scores <<<B * CHUNKS, 256, 0, stream>>>(x, partials);
    k_softmax<<<B,          64,  0, stream>>>(partials, alpha);
    k_apply  <<<B * 256,    256, 0, stream>>>(x, alpha, out);
}